// Round 5
// baseline (2692.454 us; speedup 1.0000x reference)
//
#include <hip/hip_runtime.h>
#include <hip/hip_fp16.h>
#include <math.h>

#define B_ 64
#define N_ 512
#define H_ 32
#define E_ 4
#define NSTEPS 5
#define KTOT 2048       // N_*E_
#define KSPLIT 8
#define KCHUNK 256      // KTOT / KSPLIT (fallback path)
#define ASLAB (B_*N_*H_)   // floats per partial-a slab (fallback path)

typedef _Float16 half8 __attribute__((ext_vector_type(8)));
typedef float   f32x4 __attribute__((ext_vector_type(4)));

// ---------------------------------------------------------------- init h <- x
__global__ __launch_bounds__(256) void k_init_h(const float* __restrict__ x,
                                                float* __restrict__ h) {
    int i = blockIdx.x * blockDim.x + threadIdx.x;   // 262144 float4s
    ((f32x4*)h)[i] = ((const f32x4*)x)[i];
}

// ================================================================ NEW PATH
// a_in[b] = sum_e (m_e[b] @ h[b]) @ W_in_e^T + bias via msum, where
// m_e[b] = m[b][:, dir*2048 + e*512 : +512].  Big GEMM: (512x512)@(512x32).

// ---------------------------------------------------------------- m pre-pack (once)
// Pack m into MFMA A-fragment order, split fp16 hi/lo; also msum[b,n,dir,e].
// Fragment: pHi[(((g*8+p)*4+w)*16 + it)*512 + lane*8 + j]
//   = fp16( m[b][p*64+w*16+(lane&15)][dir*2048+e*512 + it*32+(lane>>4)*8+j] )
// with g = (b*2+dir)*4+e.  Einsum reads 1KB/wave sequential.
__global__ __launch_bounds__(256) void k_pack(const float* __restrict__ m,
                                              _Float16* __restrict__ pHi,
                                              _Float16* __restrict__ pLo,
                                              float* __restrict__ msum) {
    __shared__ __align__(16) char lds[65536];   // 4 waves x 16KB, swizzled
    int p = blockIdx.x;            // 0..7
    int g = blockIdx.y;            // 0..511
    int b = g >> 3, dir = (g >> 2) & 1, e = g & 3;
    int tid = threadIdx.x;
    int w = tid >> 6, lane = tid & 63, l15 = lane & 15, quad = lane >> 4;

    const float* mbase = m + ((size_t)(b * N_ + p * 64 + w * 16) * (2 * KTOT))
                           + dir * KTOT + e * 512;
    char* myl = lds + w * 16384;
    size_t obase = ((((size_t)g * 8 + p) * 4 + w) * 16) * 512;
    float s_acc = 0.f;

    for (int half = 0; half < 2; half++) {
        __syncthreads();
        // stage 16 rows x 256 floats (1 instr per row, swizzled rows)
        for (int r = 0; r < 16; r++) {
            f32x4 v = *(const f32x4*)(mbase + (size_t)r * (2 * KTOT)
                                      + half * 256 + lane * 4);
            int byte = r * 1024 + ((lane * 16) ^ ((r & 7) << 4));
            *(f32x4*)(myl + byte) = v;
        }
        __syncthreads();
        // emit fragments
        for (int it = 0; it < 8; it++) {
            int kf = it * 32 + quad * 8;
            int swz = (l15 & 7) << 4;
            int byte0 = l15 * 1024 + ((kf * 4) ^ swz);
            int byte1 = l15 * 1024 + (((kf + 4) * 4) ^ swz);
            f32x4 v0 = *(const f32x4*)(myl + byte0);
            f32x4 v1 = *(const f32x4*)(myl + byte1);
            half8 hi, lo;
#pragma unroll
            for (int j = 0; j < 4; j++) {
                float v = v0[j];
                _Float16 hh = (_Float16)v;
                hi[j] = hh; lo[j] = (_Float16)(v - (float)hh);
                s_acc += v;
            }
#pragma unroll
            for (int j = 0; j < 4; j++) {
                float v = v1[j];
                _Float16 hh = (_Float16)v;
                hi[j + 4] = hh; lo[j + 4] = (_Float16)(v - (float)hh);
                s_acc += v;
            }
            size_t o = obase + (size_t)(half * 8 + it) * 512 + lane * 8;
            *(half8*)(pHi + o) = hi;
            *(half8*)(pLo + o) = lo;
        }
    }
    // reduce the 4 quads of each row -> msum[b][n][dir][e]
    s_acc += __shfl_xor(s_acc, 16);
    s_acc += __shfl_xor(s_acc, 32);
    if (quad == 0) {
        int n = p * 64 + w * 16 + l15;
        msum[(((size_t)b * N_ + n) * 2 + dir) * 4 + e] = s_acc;
    }
}

// ---------------------------------------------------------------- big GEMM
// block = (e + 4*kh, b, dir): G[(g*2+kh)][n][h'] += m_e[:, kh-half] @ h[kh-half]
// A: packed sequential hi/lo fragments.  B: h staged transposed hi/lo in LDS.
__global__ __launch_bounds__(256) void k_gemm(const float* __restrict__ h,
                                              const _Float16* __restrict__ pHi,
                                              const _Float16* __restrict__ pLo,
                                              float* __restrict__ G) {
    int eh  = blockIdx.x;          // 0..7
    int e   = eh & 3, kh = eh >> 2;
    int b   = blockIdx.y;
    int dir = blockIdx.z;
    int g   = (b * 2 + dir) * 4 + e;
    int tid = threadIdx.x;
    int w = tid >> 6, lane = tid & 63, l15 = lane & 15, quad = lane >> 4;

    __shared__ __align__(16) char hT[32768];  // [plane2][c 32][n' 256] fp16 swz

    // stage h[b][kh*256+n'][c] -> hT[c][n'] (hi/lo planes)
    for (int i = tid; i < 2048; i += 256) {
        int np = i >> 3, cg = i & 7;
        f32x4 v = *(const f32x4*)(h + ((size_t)b * N_ + kh * 256 + np) * H_ + cg * 4);
#pragma unroll
        for (int j = 0; j < 4; j++) {
            int c = cg * 4 + j;
            float vv = v[j];
            _Float16 hh = (_Float16)vv;
            _Float16 ll = (_Float16)(vv - (float)hh);
            int base = c * 512 + ((np * 2) ^ ((c & 7) << 4));
            *(_Float16*)(hT + base) = hh;
            *(_Float16*)(hT + 16384 + base) = ll;
        }
    }
    __syncthreads();

    float* Gout = G + ((size_t)g * 2 + kh) * 16384;
    int swz = (l15 & 7) << 4;

    for (int p = 0; p < 8; p++) {
        size_t abase = ((((size_t)g * 8 + p) * 4 + w) * 16 + kh * 8) * 512
                       + (size_t)lane * 8;
        f32x4 acc0 = {0.f,0.f,0.f,0.f}, acc1 = {0.f,0.f,0.f,0.f};

#pragma unroll 2
        for (int it = 0; it < 8; it++) {
            half8 Ahi = *(const half8*)(pHi + abase + (size_t)it * 512);
            half8 Alo = *(const half8*)(pLo + abase + (size_t)it * 512);

            int kb = (it * 32 + quad * 8) * 2;     // byte offset in c-row
            int o0 = l15 * 512        + (kb ^ swz);
            int o1 = (l15 + 16) * 512 + (kb ^ swz);
            half8 Bhi0 = *(const half8*)(hT + o0);
            half8 Bhi1 = *(const half8*)(hT + o1);
            half8 Blo0 = *(const half8*)(hT + 16384 + o0);
            half8 Blo1 = *(const half8*)(hT + 16384 + o1);

            acc0 = __builtin_amdgcn_mfma_f32_16x16x32_f16(Ahi, Bhi0, acc0, 0, 0, 0);
            acc1 = __builtin_amdgcn_mfma_f32_16x16x32_f16(Ahi, Bhi1, acc1, 0, 0, 0);
            acc0 = __builtin_amdgcn_mfma_f32_16x16x32_f16(Ahi, Blo0, acc0, 0, 0, 0);
            acc1 = __builtin_amdgcn_mfma_f32_16x16x32_f16(Ahi, Blo1, acc1, 0, 0, 0);
            acc0 = __builtin_amdgcn_mfma_f32_16x16x32_f16(Alo, Bhi0, acc0, 0, 0, 0);
            acc1 = __builtin_amdgcn_mfma_f32_16x16x32_f16(Alo, Bhi1, acc1, 0, 0, 0);
        }

#pragma unroll
        for (int r = 0; r < 4; r++) {
            int rr = p * 64 + w * 16 + quad * 4 + r;
            Gout[(size_t)rr * 32 + l15]      = acc0[r];
            Gout[(size_t)rr * 32 + 16 + l15] = acc1[r];
        }
    }
}

// ---------------------------------------------------------------- GRU gates (new)
// a[dir][n,h] = sum_e (sum_kh G) @ W_e^T + sum_e msum*bias, then z/r/t gates.
__global__ __launch_bounds__(256) void k_gate2(const float* __restrict__ G,
                                               const float* __restrict__ msum,
                                               float* __restrict__ hstate,
                                               const float* __restrict__ W_in,
                                               const float* __restrict__ b_in,
                                               const float* __restrict__ W_out,
                                               const float* __restrict__ b_out,
                                               const float* __restrict__ Wz,
                                               const float* __restrict__ bz,
                                               const float* __restrict__ Wr,
                                               const float* __restrict__ br,
                                               const float* __restrict__ Wt,
                                               const float* __restrict__ bt) {
    __shared__ float Gs[8][256];   // [row][dir*128 + e*32 + h']
    __shared__ float cat[8][96];
    __shared__ float rh[8][32];
    int base = blockIdx.x * 8;     // flattened row b*512+n
    int t = threadIdx.x;
    int b = base >> 9;

    for (int i = t; i < 2048; i += 256) {
        int r = i >> 8, c = i & 255;
        int dir = c >> 7, e = (c >> 5) & 3, hp = c & 31;
        int n = (base + r) & 511;
        size_t gg = ((size_t)(b * 2 + dir) * 4 + e) * 2;
        size_t off = (size_t)n * 32 + hp;
        Gs[r][c] = G[gg * 16384 + off] + G[(gg + 1) * 16384 + off];
    }
    __syncthreads();

    int r = t >> 5, i = t & 31;
    {
        int n = (base + r) & 511;
        const float* ms = msum + ((size_t)b * N_ + n) * 8;   // [dir][e]
        float a0 = 0.f, a1 = 0.f;
#pragma unroll
        for (int e = 0; e < 4; e++) {
            int he = i * 4 + e;
            a0 += ms[e]     * b_in[he];
            a1 += ms[4 + e] * b_out[he];
            const f32x4* wi = (const f32x4*)(W_in  + (size_t)he * 32);
            const f32x4* wo = (const f32x4*)(W_out + (size_t)he * 32);
            const f32x4* g0 = (const f32x4*)&Gs[r][e * 32];
            const f32x4* g1 = (const f32x4*)&Gs[r][128 + e * 32];
#pragma unroll
            for (int q = 0; q < 8; q++) {
                f32x4 gv0 = g0[q], wv0 = wi[q];
                f32x4 gv1 = g1[q], wv1 = wo[q];
                a0 += gv0[0]*wv0[0] + gv0[1]*wv0[1] + gv0[2]*wv0[2] + gv0[3]*wv0[3];
                a1 += gv1[0]*wv1[0] + gv1[1]*wv1[1] + gv1[2]*wv1[2] + gv1[3]*wv1[3];
            }
        }
        cat[r][i]      = a0;
        cat[r][32 + i] = a1;
        cat[r][64 + i] = hstate[(size_t)(base + r) * 32 + i];
    }
    __syncthreads();

    float az = bz[i], ar = br[i];
    const f32x4* wzr = (const f32x4*)(Wz + (size_t)i * 96);
    const f32x4* wrr = (const f32x4*)(Wr + (size_t)i * 96);
    const f32x4* crow = (const f32x4*)cat[r];
#pragma unroll
    for (int kc = 0; kc < 24; kc++) {
        f32x4 cv = crow[kc];
        f32x4 wz = wzr[kc];
        f32x4 wr = wrr[kc];
        az += cv[0]*wz[0] + cv[1]*wz[1] + cv[2]*wz[2] + cv[3]*wz[3];
        ar += cv[0]*wr[0] + cv[1]*wr[1] + cv[2]*wr[2] + cv[3]*wr[3];
    }
    float z  = 1.f / (1.f + __expf(-az));
    float rg = 1.f / (1.f + __expf(-ar));
    float hold = cat[r][64 + i];
    rh[r][i] = rg * hold;
    __syncthreads();

    float at = bt[i];
    const f32x4* wtr = (const f32x4*)(Wt + (size_t)i * 96);
#pragma unroll
    for (int kc = 0; kc < 16; kc++) {
        f32x4 cv = crow[kc];
        f32x4 wt = wtr[kc];
        at += cv[0]*wt[0] + cv[1]*wt[1] + cv[2]*wt[2] + cv[3]*wt[3];
    }
    const f32x4* rrow = (const f32x4*)rh[r];
#pragma unroll
    for (int kc = 0; kc < 8; kc++) {
        f32x4 cv = rrow[kc];
        f32x4 wt = wtr[16 + kc];
        at += cv[0]*wt[0] + cv[1]*wt[1] + cv[2]*wt[2] + cv[3]*wt[3];
    }
    float hh = tanhf(at);
    hstate[(size_t)(base + r) * 32 + i] = (1.f - z) * hold + z * hh;
}

// ================================================================ FALLBACK PATH
// (verbatim round-4 kernels, used only if ws_size is too small)
__global__ __launch_bounds__(256) void k_s(const float* __restrict__ hstate,
                                           const float* __restrict__ W_in,
                                           const float* __restrict__ b_in,
                                           const float* __restrict__ W_out,
                                           const float* __restrict__ b_out,
                                           _Float16* __restrict__ sT_in_hi,
                                           _Float16* __restrict__ sT_in_lo,
                                           _Float16* __restrict__ sT_out_hi,
                                           _Float16* __restrict__ sT_out_lo) {
    int b  = blockIdx.x >> 3;
    int n0 = (blockIdx.x & 7) * 64;
    int lane = threadIdx.x & 63;
    int w = __builtin_amdgcn_readfirstlane((int)(threadIdx.x >> 6));
    int n = n0 + lane;

    const float* hrow = hstate + ((size_t)b * N_ + n) * H_;
    f32x4 hv[8];
#pragma unroll
    for (int c = 0; c < 8; c++) hv[c] = ((const f32x4*)hrow)[c];

#pragma unroll 4
    for (int o = 0; o < 32; o++) {
        int he = w * 32 + o;
        const f32x4* wr = (const f32x4*)(W_in + (size_t)he * H_);
        float acc = b_in[he];
#pragma unroll
        for (int c = 0; c < 8; c++) {
            f32x4 wv = wr[c];
            acc += hv[c][0]*wv[0] + hv[c][1]*wv[1] + hv[c][2]*wv[2] + hv[c][3]*wv[3];
        }
        int hh = he >> 2, e = he & 3;
        size_t idx = ((size_t)b * H_ + hh) * KTOT + e * N_ + n;
        _Float16 hi = (_Float16)acc;
        sT_in_hi[idx] = hi;
        sT_in_lo[idx] = (_Float16)(acc - (float)hi);
    }
#pragma unroll 4
    for (int o = 0; o < 32; o++) {
        int he = w * 32 + o;
        const f32x4* wr = (const f32x4*)(W_out + (size_t)he * H_);
        float acc = b_out[he];
#pragma unroll
        for (int c = 0; c < 8; c++) {
            f32x4 wv = wr[c];
            acc += hv[c][0]*wv[0] + hv[c][1]*wv[1] + hv[c][2]*wv[2] + hv[c][3]*wv[3];
        }
        int hh = he >> 2, e = he & 3;
        size_t idx = ((size_t)b * H_ + hh) * KTOT + e * N_ + n;
        _Float16 hi = (_Float16)acc;
        sT_out_hi[idx] = hi;
        sT_out_lo[idx] = (_Float16)(acc - (float)hi);
    }
}

__global__ __launch_bounds__(256) void k_einsum_l(const float* __restrict__ m,
                                                  const _Float16* __restrict__ sT_in_hi,
                                                  const _Float16* __restrict__ sT_in_lo,
                                                  const _Float16* __restrict__ sT_out_hi,
                                                  const _Float16* __restrict__ sT_out_lo,
                                                  float* __restrict__ apart) {
    int split = blockIdx.x;
    int b     = blockIdx.y;
    int dir   = blockIdx.z;
    int tid   = threadIdx.x;
    int w     = tid >> 6;
    int lane  = tid & 63;
    int l15   = lane & 15;
    int quad  = lane >> 4;

    __shared__ __align__(16) char smem[32768];

    const _Float16* sHi = (dir ? sT_out_hi : sT_in_hi)
                          + (size_t)b * H_ * KTOT + split * KCHUNK;
    const _Float16* sLo = (dir ? sT_out_lo : sT_in_lo)
                          + (size_t)b * H_ * KTOT + split * KCHUNK;

    for (int i = tid; i < 2048; i += 256) {
        int plane = i >> 10, row = (i >> 5) & 31, c16 = i & 31;
        const _Float16* src = (plane ? sLo : sHi) + (size_t)row * KTOT + c16 * 8;
        half8 v = *(const half8*)src;
        int byte = plane * 16384 + row * 512 + ((c16 * 16) ^ ((row & 7) << 4));
        *(half8*)(smem + byte) = v;
    }
    __syncthreads();

    float* aout = apart + (size_t)(dir * KSPLIT + split) * ASLAB;
    int swz0 = (l15 & 7) << 4;

#pragma unroll 2
    for (int pass = 0; pass < 8; pass++) {
        int n0 = pass * 64;
        const float* mrow = m + ((size_t)b * N_ + n0 + w * 16 + l15) * (2 * KTOT)
                              + (size_t)dir * KTOT + split * KCHUNK;

        f32x4 acc0 = {0.f,0.f,0.f,0.f}, acc1 = {0.f,0.f,0.f,0.f};

#pragma unroll 2
        for (int it = 0; it < 8; it++) {
            int ko = it * 32 + quad * 8;
            f32x4 a0 = *(const f32x4*)(mrow + ko);
            f32x4 a1 = *(const f32x4*)(mrow + ko + 4);

            int kb = it * 64 + quad * 16;
            int o0 = l15 * 512        + (kb ^ swz0);
            int o1 = (l15 + 16) * 512 + (kb ^ swz0);
            half8 Bhi0 = *(const half8*)(smem + o0);
            half8 Bhi1 = *(const half8*)(smem + o1);
            half8 Blo0 = *(const half8*)(smem + 16384 + o0);
            half8 Blo1 = *(const half8*)(smem + 16384 + o1);

            half8 Ahi, Alo;
#pragma unroll
            for (int j = 0; j < 4; j++) {
                float v0 = a0[j], v1 = a1[j];
                _Float16 h0 = (_Float16)v0, h1 = (_Float16)v1;
                Ahi[j]     = h0;
                Ahi[j + 4] = h1;
                Alo[j]     = (_Float16)(v0 - (float)h0);
                Alo[j + 4] = (_Float16)(v1 - (float)h1);
            }
            acc0 = __builtin_amdgcn_mfma_f32_16x16x32_f16(Ahi, Bhi0, acc0, 0, 0, 0);
            acc1 = __builtin_amdgcn_mfma_f32_16x16x32_f16(Ahi, Bhi1, acc1, 0, 0, 0);
            acc0 = __builtin_amdgcn_mfma_f32_16x16x32_f16(Ahi, Blo0, acc0, 0, 0, 0);
            acc1 = __builtin_amdgcn_mfma_f32_16x16x32_f16(Ahi, Blo1, acc1, 0, 0, 0);
            acc0 = __builtin_amdgcn_mfma_f32_16x16x32_f16(Alo, Bhi0, acc0, 0, 0, 0);
            acc1 = __builtin_amdgcn_mfma_f32_16x16x32_f16(Alo, Bhi1, acc1, 0, 0, 0);
        }

#pragma unroll
        for (int r = 0; r < 4; r++) {
            size_t rr = (size_t)b * N_ + (n0 + w * 16 + quad * 4 + r);
            aout[rr * H_ + l15]      = acc0[r];
            aout[rr * H_ + 16 + l15] = acc1[r];
        }
    }
}

__global__ __launch_bounds__(256) void k_gate(const float* __restrict__ apart,
                                              float* __restrict__ hstate,
                                              const float* __restrict__ Wz,
                                              const float* __restrict__ bz,
                                              const float* __restrict__ Wr,
                                              const float* __restrict__ br,
                                              const float* __restrict__ Wt,
                                              const float* __restrict__ bt) {
    __shared__ float cat[8][96];
    __shared__ float rh[8][32];
    int base = blockIdx.x * 8;
    int t = threadIdx.x;

    for (int idx = t; idx < 768; idx += 256) {
        int r = idx / 96, c = idx - r * 96;
        size_t row = (size_t)(base + r);
        float v;
        if (c < 64) {
            int d = c >> 5;
            const float* p = apart + (size_t)d * KSPLIT * ASLAB + row * 32 + (c & 31);
            v = p[0];
#pragma unroll
            for (int s2 = 1; s2 < KSPLIT; s2++) v += p[(size_t)s2 * ASLAB];
        } else {
            v = hstate[row * 32 + (c - 64)];
        }
        cat[r][c] = v;
    }
    __syncthreads();

    int r = t >> 5, i = t & 31;
    float az = bz[i], ar = br[i];
    const f32x4* wzr = (const f32x4*)(Wz + (size_t)i * 96);
    const f32x4* wrr = (const f32x4*)(Wr + (size_t)i * 96);
    const f32x4* crow = (const f32x4*)cat[r];
#pragma unroll
    for (int kc = 0; kc < 24; kc++) {
        f32x4 cv = crow[kc];
        f32x4 wz = wzr[kc];
        f32x4 wr = wrr[kc];
        az += cv[0]*wz[0] + cv[1]*wz[1] + cv[2]*wz[2] + cv[3]*wz[3];
        ar += cv[0]*wr[0] + cv[1]*wr[1] + cv[2]*wr[2] + cv[3]*wr[3];
    }
    float z  = 1.f / (1.f + __expf(-az));
    float rg = 1.f / (1.f + __expf(-ar));
    float hold = cat[r][64 + i];
    rh[r][i] = rg * hold;
    __syncthreads();

    float at = bt[i];
    const f32x4* wtr = (const f32x4*)(Wt + (size_t)i * 96);
#pragma unroll
    for (int kc = 0; kc < 16; kc++) {
        f32x4 cv = crow[kc];
        f32x4 wt = wtr[kc];
        at += cv[0]*wt[0] + cv[1]*wt[1] + cv[2]*wt[2] + cv[3]*wt[3];
    }
    const f32x4* rrow = (const f32x4*)rh[r];
#pragma unroll
    for (int kc = 0; kc < 8; kc++) {
        f32x4 cv = rrow[kc];
        f32x4 wt = wtr[16 + kc];
        at += cv[0]*wt[0] + cv[1]*wt[1] + cv[2]*wt[2] + cv[3]*wt[3];
    }
    float hh = tanhf(at);
    hstate[(size_t)(base + r) * 32 + i] = (1.f - z) * hold + z * hh;
}

// ---------------------------------------------------------------- readout
__global__ __launch_bounds__(256) void k_final(const float* __restrict__ hstate,
                                               const float* __restrict__ a,
                                               const float* __restrict__ W1,
                                               const float* __restrict__ b1,
                                               const float* __restrict__ W2,
                                               const float* __restrict__ b2,
                                               float* __restrict__ out) {
    __shared__ float hl[8][32];
    __shared__ float as[8];
    int base = blockIdx.x * 8;
    int t = threadIdx.x;
    {
        int r = t >> 5, c = t & 31;
        hl[r][c] = hstate[(size_t)(base + r) * 32 + c];
        if (t < 8) as[t] = a[base + t];
    }
    __syncthreads();
    int r = t >> 5, j = t & 31;
    float acc = b1[j];
    const float* w1r = W1 + (size_t)j * 33;
#pragma unroll
    for (int i2 = 0; i2 < 32; i2++) acc += hl[r][i2] * w1r[i2];
    acc += as[r] * w1r[32];
    float o = tanhf(acc) * W2[j];
#pragma unroll
    for (int off = 16; off; off >>= 1) o += __shfl_xor(o, off, 32);
    if (j == 0) out[base + r] = o + b2[0];
}

// ---------------------------------------------------------------- launcher
extern "C" void kernel_launch(void* const* d_in, const int* in_sizes, int n_in,
                              void* d_out, int out_size, void* d_ws, size_t ws_size,
                              hipStream_t stream) {
    const float* x     = (const float*)d_in[0];
    const float* a     = (const float*)d_in[1];
    const float* m     = (const float*)d_in[2];
    const float* W_in  = (const float*)d_in[3];
    const float* b_in  = (const float*)d_in[4];
    const float* W_out = (const float*)d_in[5];
    const float* b_out = (const float*)d_in[6];
    const float* Wz    = (const float*)d_in[7];
    const float* bz    = (const float*)d_in[8];
    const float* Wr    = (const float*)d_in[9];
    const float* br    = (const float*)d_in[10];
    const float* Wt    = (const float*)d_in[11];
    const float* bt    = (const float*)d_in[12];
    const float* W1    = (const float*)d_in[13];
    const float* b1    = (const float*)d_in[14];
    const float* W2    = (const float*)d_in[15];
    const float* b2    = (const float*)d_in[16];
    float* out = (float*)d_out;

    char* ws = (char*)d_ws;
    float* h = (float*)(ws);                                      // 4 MB

    const int use_new = (ws_size >= ((size_t)592 << 20));

    k_init_h<<<1024, 256, 0, stream>>>(x, h);

    if (use_new) {
        float*    G      = (float*)(ws + ((size_t)4  << 20));     // 64 MB
        float*    msum   = (float*)(ws + ((size_t)68 << 20));     // 1 MB
        _Float16* pHi    = (_Float16*)(ws + ((size_t)80  << 20)); // 256 MB
        _Float16* pLo    = (_Float16*)(ws + ((size_t)336 << 20)); // 256 MB (592)

        k_pack<<<dim3(8, 512), 256, 0, stream>>>(m, pHi, pLo, msum);
        for (int s = 0; s < NSTEPS; s++) {
            k_gemm<<<dim3(8, 64, 2), 256, 0, stream>>>(h, pHi, pLo, G);
            k_gate2<<<4096, 256, 0, stream>>>(G, msum, h, W_in, b_in, W_out, b_out,
                                              Wz, bz, Wr, br, Wt, bt);
        }
    } else {
        float*    apart     = (float*)(ws + ((size_t)4  << 20));      // 64 MB
        _Float16* sT_in_hi  = (_Float16*)(ws + ((size_t)68 << 20));
        _Float16* sT_in_lo  = (_Float16*)(ws + ((size_t)76 << 20));
        _Float16* sT_out_hi = (_Float16*)(ws + ((size_t)84 << 20));
        _Float16* sT_out_lo = (_Float16*)(ws + ((size_t)92 << 20));
        for (int s = 0; s < NSTEPS; s++) {
            k_s<<<512, 256, 0, stream>>>(h, W_in, b_in, W_out, b_out,
                                         sT_in_hi, sT_in_lo, sT_out_hi, sT_out_lo);
            k_einsum_l<<<dim3(KSPLIT, 64, 2), 256, 0, stream>>>(m, sT_in_hi, sT_in_lo,
                                                                sT_out_hi, sT_out_lo,
                                                                apart);
            k_gate<<<4096, 256, 0, stream>>>(apart, h, Wz, bz, Wr, br, Wt, bt);
        }
    }
    k_final<<<4096, 256, 0, stream>>>(h, a, W1, b1, W2, b2, out);
}